// Round 12
// baseline (566.523 us; speedup 1.0000x reference)
//
#include <hip/hip_runtime.h>
#include <math.h>

#define BN_EPS 1e-5f

typedef _Float16 f16;
typedef __attribute__((ext_vector_type(4))) _Float16 f16x4;
typedef __attribute__((ext_vector_type(8))) _Float16 f16x8;
typedef __attribute__((ext_vector_type(4))) float f32x4;

// ---------------- edge dtype handling (int32 vs int64) ----------------
__device__ __forceinline__ int edge_at(const void* ei, long long idx, int is64) {
    if (is64) return (int)((const long long*)ei)[idx];
    return ((const int*)ei)[idx];
}

// ------- init: zero degrees + scalars + done-counter + int64-detect --------
__global__ void init_kernel(const void* ei, int* flag, int* deg_i,
                            double* scal, int* done, int n) {
    int i = blockIdx.x * 256 + threadIdx.x;
    if (i < n) deg_i[i] = 0;
    if (blockIdx.x == 0 && threadIdx.x == 0) {
        scal[0] = 0.0; scal[1] = 0.0;
        *done = 0;
        const int* p = (const int*)ei;
        int f = 1;
        for (int k = 0; k < 64; k++)
            if (p[2 * k + 1] != 0) { f = 0; break; }
        *flag = f;          // int64 iff every high word of 64 entries is 0
    }
}

// ---- degree count; atomic's old value IS this edge's rank within dst ------
__global__ void degi_kernel(const void* ei, const int* flag, int* deg_i,
                            int* __restrict__ rank, int E) {
    const int base = blockIdx.x * 1024 + threadIdx.x;
    const int is64 = *flag;
    #pragma unroll
    for (int k = 0; k < 4; k++) {
        int e = base + k * 256;
        if (e < E) {
            int d = edge_at(ei, (long long)E + e, is64);
            rank[e] = atomicAdd(&deg_i[d], 1);   // coalesced rank write
        }
    }
}

// ---------------- exclusive scan (2048 elems/block) ------------------------
__global__ __launch_bounds__(256) void scan1_kernel(
    const int* __restrict__ in, int* __restrict__ excl, int* bsum, int n) {
    __shared__ int sh[256];
    const int tid = threadIdx.x;
    const int base = blockIdx.x * 2048 + tid * 8;
    int v[8];
    #pragma unroll
    for (int i = 0; i < 8; i++) v[i] = (base + i < n) ? in[base + i] : 0;
    int tsum = 0;
    #pragma unroll
    for (int i = 0; i < 8; i++) { int t = v[i]; v[i] = tsum; tsum += t; }
    sh[tid] = tsum;
    __syncthreads();
    for (int off = 1; off < 256; off <<= 1) {
        int t = 0;
        if (tid >= off) t = sh[tid - off];
        __syncthreads();
        if (tid >= off) sh[tid] += t;
        __syncthreads();
    }
    int texcl = sh[tid] - tsum;
    #pragma unroll
    for (int i = 0; i < 8; i++)
        if (base + i < n) excl[base + i] = texcl + v[i];
    if (tid == 255 && bsum) bsum[blockIdx.x] = sh[255];
}

// scan3 + dinv fused
__global__ void scan3_kernel(int* rowptr, const int* __restrict__ boff,
                             const int* __restrict__ deg_i,
                             float* __restrict__ dinv, int n, int E) {
    int i = blockIdx.x * 256 + threadIdx.x;
    if (i < n) {
        rowptr[i] = rowptr[i] + boff[i >> 11];
        dinv[i] = rsqrtf((float)(deg_i[i] + 1));   // +1 self-loop
    }
    if (i == 0) rowptr[n] = E;
}

// ---- atomic-free fill: pos = rowptr[dst] + rank; nt store ------------------
__global__ void fill_kernel(const void* ei, const int* flag,
                            const int* __restrict__ rowptr,
                            const int* __restrict__ rank,
                            int* __restrict__ col, int E) {
    const int base = blockIdx.x * 1024 + threadIdx.x;
    const int is64 = *flag;
    #pragma unroll
    for (int k = 0; k < 4; k++) {
        int e = base + k * 256;
        if (e < E) {
            int s = edge_at(ei, e, is64);
            int d = edge_at(ei, (long long)E + e, is64);
            __builtin_nontemporal_store(s, &col[rowptr[d] + rank[e]]);
        }
    }
}

// ---- W prep: W1,W2 transpose + f16 hi/lo split; W3 [128][40]->[48][128] ----
__global__ __launch_bounds__(256) void prep_w_kernel(
    const float* __restrict__ W1, f16* __restrict__ Wt1h, f16* __restrict__ Wt1l,
    const float* __restrict__ W2, f16* __restrict__ Wt2h, f16* __restrict__ Wt2l,
    const float* __restrict__ W3, f16* __restrict__ Wt3h, f16* __restrict__ Wt3l) {
    const int total = 2 * 16384 + 48 * 128;
    for (int f = blockIdx.x * 256 + threadIdx.x; f < total;
         f += gridDim.x * 256) {
        if (f < 2 * 16384) {
            int which = f >> 14, g = f & 16383;
            int k = g >> 7, nn = g & 127;
            const float* W = which ? W2 : W1;
            f16* Wh = which ? Wt2h : Wt1h;
            f16* Wl = which ? Wt2l : Wt1l;
            float wv = W[g];
            f16 h = (f16)wv;
            Wh[nn * 128 + k] = h;
            Wl[nn * 128 + k] = (f16)(wv - (float)h);
        } else {
            int g = f - 2 * 16384;        // 0..6143
            int nn = g >> 7, k = g & 127; // col nn (0..47), row k
            float wv = (nn < 40) ? W3[k * 40 + nn] : 0.f;
            f16 h = (f16)wv;
            Wt3h[g] = h;
            Wt3l[g] = (f16)(wv - (float)h);
        }
    }
}

// ---------------- layer-1 MFMA GEMM: fp32 in, fp16 out, 2-pass ------------
#define APAD 40   // padded k-stride (halves): 80B rows
__global__ __launch_bounds__(256) void gemm_l1_kernel(
    const float* __restrict__ X, const f16* __restrict__ Wth,
    const f16* __restrict__ Wtl, const float* __restrict__ dinv,
    f16* __restrict__ out, int M) {
    __shared__ f16 Ah[128 * APAD];
    __shared__ f16 Bh[128 * APAD];
    __shared__ f16 Bl[128 * APAD];
    const int t = threadIdx.x;
    const int r0 = blockIdx.x * 128;
    const int w = t >> 6, lane = t & 63;
    const int m0 = (w >> 1) * 64, n0 = (w & 1) * 64;
    const int fr = lane & 15;
    const int kb = (lane >> 4) * 8;

    f32x4 acc[4][4];
    #pragma unroll
    for (int i = 0; i < 4; i++)
        #pragma unroll
        for (int j = 0; j < 4; j++) acc[i][j] = (f32x4)0.f;

    for (int k0 = 0; k0 < 128; k0 += 32) {
        #pragma unroll
        for (int i = 0; i < 4; i++) {
            int f = t + i * 256;               // 0..1023
            int row = f >> 3, kq = (f & 7) * 4;
            float4 v = make_float4(0.f, 0.f, 0.f, 0.f);
            if (r0 + row < M)
                v = *(const float4*)&X[(size_t)(r0 + row) * 128 + k0 + kq];
            *(f16x4*)&Ah[row * APAD + kq] =
                (f16x4){(f16)v.x, (f16)v.y, (f16)v.z, (f16)v.w};
        }
        #pragma unroll
        for (int i = 0; i < 2; i++) {
            int f = t + i * 256;               // 0..511
            int nrow = f >> 2, kq = (f & 3) * 8;
            int gb = nrow * 128 + k0 + kq;
            int lb = nrow * APAD + kq;
            *(uint4*)&Bh[lb] = *(const uint4*)&Wth[gb];
            *(uint4*)&Bl[lb] = *(const uint4*)&Wtl[gb];
        }
        __syncthreads();

        f16x8 a0[4], b0[4], xx[4];
        #pragma unroll
        for (int i = 0; i < 4; i++) {
            a0[i] = *(const f16x8*)&Ah[(m0 + i * 16 + fr) * APAD + kb];
            b0[i] = *(const f16x8*)&Bh[(n0 + i * 16 + fr) * APAD + kb];
        }
        #pragma unroll
        for (int i = 0; i < 4; i++)
            #pragma unroll
            for (int j = 0; j < 4; j++)
                acc[i][j] = __builtin_amdgcn_mfma_f32_16x16x32_f16(
                    a0[i], b0[j], acc[i][j], 0, 0, 0);
        #pragma unroll
        for (int i = 0; i < 4; i++)
            xx[i] = *(const f16x8*)&Bl[(n0 + i * 16 + fr) * APAD + kb];
        #pragma unroll
        for (int i = 0; i < 4; i++)
            #pragma unroll
            for (int j = 0; j < 4; j++)
                acc[i][j] = __builtin_amdgcn_mfma_f32_16x16x32_f16(
                    a0[i], xx[j], acc[i][j], 0, 0, 0);
        __syncthreads();
    }

    // C/D layout: col=lane&15, row=(lane>>4)*4+reg (m89-verified)
    #pragma unroll
    for (int i = 0; i < 4; i++) {
        #pragma unroll
        for (int r = 0; r < 4; r++) {
            int row = r0 + m0 + i * 16 + (lane >> 4) * 4 + r;
            if (row < M) {
                float di = dinv[row];
                #pragma unroll
                for (int j = 0; j < 4; j++)
                    out[(size_t)row * 128 + n0 + j * 16 + fr] =
                        (f16)(acc[i][j][r] * di);
            }
        }
    }
}

// ---------------- layer-2 MFMA GEMM: fp16 in, fp16 out, 2-pass ------------
__global__ __launch_bounds__(256) void gemm_l2_kernel(
    const f16* __restrict__ X, const f16* __restrict__ Wth,
    const f16* __restrict__ Wtl, const float* __restrict__ dinv,
    f16* __restrict__ out, int M) {
    __shared__ f16 Ax[128 * APAD];
    __shared__ f16 Bh[128 * APAD];
    __shared__ f16 Bl[128 * APAD];
    const int t = threadIdx.x;
    const int r0 = blockIdx.x * 128;
    const int w = t >> 6, lane = t & 63;
    const int m0 = (w >> 1) * 64, n0 = (w & 1) * 64;
    const int fr = lane & 15;
    const int kb = (lane >> 4) * 8;

    f32x4 acc[4][4];
    #pragma unroll
    for (int i = 0; i < 4; i++)
        #pragma unroll
        for (int j = 0; j < 4; j++) acc[i][j] = (f32x4)0.f;

    for (int k0 = 0; k0 < 128; k0 += 32) {
        #pragma unroll
        for (int i = 0; i < 2; i++) {
            int f = t + i * 256;               // 0..511
            int row = f >> 2, kq = (f & 3) * 8;
            uint4 v = make_uint4(0u, 0u, 0u, 0u);
            if (r0 + row < M)
                v = *(const uint4*)&X[(size_t)(r0 + row) * 128 + k0 + kq];
            *(uint4*)&Ax[row * APAD + kq] = v;
        }
        #pragma unroll
        for (int i = 0; i < 2; i++) {
            int f = t + i * 256;
            int nrow = f >> 2, kq = (f & 3) * 8;
            int gb = nrow * 128 + k0 + kq;
            int lb = nrow * APAD + kq;
            *(uint4*)&Bh[lb] = *(const uint4*)&Wth[gb];
            *(uint4*)&Bl[lb] = *(const uint4*)&Wtl[gb];
        }
        __syncthreads();

        f16x8 a0[4], b0[4], xx[4];
        #pragma unroll
        for (int i = 0; i < 4; i++) {
            a0[i] = *(const f16x8*)&Ax[(m0 + i * 16 + fr) * APAD + kb];
            b0[i] = *(const f16x8*)&Bh[(n0 + i * 16 + fr) * APAD + kb];
        }
        #pragma unroll
        for (int i = 0; i < 4; i++)
            #pragma unroll
            for (int j = 0; j < 4; j++)
                acc[i][j] = __builtin_amdgcn_mfma_f32_16x16x32_f16(
                    a0[i], b0[j], acc[i][j], 0, 0, 0);
        #pragma unroll
        for (int i = 0; i < 4; i++)
            xx[i] = *(const f16x8*)&Bl[(n0 + i * 16 + fr) * APAD + kb];
        #pragma unroll
        for (int i = 0; i < 4; i++)
            #pragma unroll
            for (int j = 0; j < 4; j++)
                acc[i][j] = __builtin_amdgcn_mfma_f32_16x16x32_f16(
                    a0[i], xx[j], acc[i][j], 0, 0, 0);
        __syncthreads();
    }

    #pragma unroll
    for (int i = 0; i < 4; i++) {
        #pragma unroll
        for (int r = 0; r < 4; r++) {
            int row = r0 + m0 + i * 16 + (lane >> 4) * 4 + r;
            if (row < M) {
                float di = dinv[row];
                #pragma unroll
                for (int j = 0; j < 4; j++)
                    out[(size_t)row * 128 + n0 + j * 16 + fr] =
                        (f16)(acc[i][j][r] * di);
            }
        }
    }
}

// ---------------- fused pull-aggregate + bias + relu + BN + relu ----------
// Half-wave (32 lanes) per node; 4-deep ILP (round-8 proven form).
__global__ __launch_bounds__(256) void agg_kernel(
    const f16* __restrict__ hs, const int* __restrict__ rowptr,
    const int* __restrict__ col, const float* __restrict__ dinv,
    const float* __restrict__ b, const float* __restrict__ g,
    const float* __restrict__ be, const float* __restrict__ m,
    const float* __restrict__ v, f16* __restrict__ h, int M) {
    const int node = blockIdx.x * 8 + (threadIdx.x >> 5);
    if (node >= M) return;
    const int lane = threadIdx.x & 31;
    const int c = lane * 4;
    const f16* __restrict__ base = hs + c;

    f16x4 sv = *(const f16x4*)&base[(size_t)node * 128];   // self-loop term
    float a0[4] = {(float)sv[0], (float)sv[1], (float)sv[2], (float)sv[3]};
    float a1[4] = {0.f, 0.f, 0.f, 0.f};
    float a2[4] = {0.f, 0.f, 0.f, 0.f};
    float a3[4] = {0.f, 0.f, 0.f, 0.f};
    const int beg = rowptr[node], end = rowptr[node + 1];
    int j = beg;
    for (; j + 3 < end; j += 4) {       // 4 independent loads in flight
        int s0 = col[j], s1 = col[j + 1], s2 = col[j + 2], s3 = col[j + 3];
        f16x4 v0 = *(const f16x4*)&base[(size_t)s0 * 128];
        f16x4 v1 = *(const f16x4*)&base[(size_t)s1 * 128];
        f16x4 v2 = *(const f16x4*)&base[(size_t)s2 * 128];
        f16x4 v3 = *(const f16x4*)&base[(size_t)s3 * 128];
        #pragma unroll
        for (int q = 0; q < 4; q++) {
            a0[q] += (float)v0[q]; a1[q] += (float)v1[q];
            a2[q] += (float)v2[q]; a3[q] += (float)v3[q];
        }
    }
    if (j + 1 < end) {                  // 2-tail
        int s0 = col[j], s1 = col[j + 1];
        f16x4 v0 = *(const f16x4*)&base[(size_t)s0 * 128];
        f16x4 v1 = *(const f16x4*)&base[(size_t)s1 * 128];
        #pragma unroll
        for (int q = 0; q < 4; q++) { a0[q] += (float)v0[q]; a1[q] += (float)v1[q]; }
        j += 2;
    }
    if (j < end) {                      // 1-tail
        int s0 = col[j];
        f16x4 v0 = *(const f16x4*)&base[(size_t)s0 * 128];
        #pragma unroll
        for (int q = 0; q < 4; q++) a0[q] += (float)v0[q];
    }
    const float di = dinv[node];
    f16x4 r;
    #pragma unroll
    for (int q = 0; q < 4; q++) {
        int cc = c + q;
        float s = (a0[q] + a1[q]) + (a2[q] + a3[q]);
        float tt = fmaxf(di * s + b[cc], 0.f);
        tt = (tt - m[cc]) * (g[cc] * rsqrtf(v[cc] + BN_EPS)) + be[cc];
        r[q] = (f16)fmaxf(tt, 0.f);
    }
    *(f16x4*)&h[(size_t)node * 128 + c] = r;
}

// ------- output GEMM (MFMA) + fused log_softmax + var finalize -------------
// Tile: 128 rows x 48 cols (40 valid). 4 waves x 32 rows. W3t read from
// global (12KB, L1/L2 resident). H staged in one 10KB LDS buffer.
__global__ __launch_bounds__(256) void gemm_out_kernel(
    const f16* __restrict__ H, const f16* __restrict__ Wt3h,
    const f16* __restrict__ Wt3l, const float* __restrict__ b3,
    float* __restrict__ out, double* __restrict__ scal,
    int* __restrict__ done, int M) {
    __shared__ f16 Ax[128 * APAD];
    const int t = threadIdx.x;
    const int r0 = blockIdx.x * 128;
    const int w = t >> 6, lane = t & 63;
    const int m0 = w * 32;
    const int fr = lane & 15;
    const int kb = (lane >> 4) * 8;

    f32x4 acc[2][3];
    #pragma unroll
    for (int i = 0; i < 2; i++)
        #pragma unroll
        for (int j = 0; j < 3; j++) acc[i][j] = (f32x4)0.f;

    for (int k0 = 0; k0 < 128; k0 += 32) {
        #pragma unroll
        for (int i = 0; i < 2; i++) {
            int f = t + i * 256;               // 0..511
            int row = f >> 2, kq = (f & 3) * 8;
            uint4 v = make_uint4(0u, 0u, 0u, 0u);
            if (r0 + row < M)
                v = *(const uint4*)&H[(size_t)(r0 + row) * 128 + k0 + kq];
            *(uint4*)&Ax[row * APAD + kq] = v;
        }
        __syncthreads();

        f16x8 a0[2], bh[3], bl[3];
        #pragma unroll
        for (int i = 0; i < 2; i++)
            a0[i] = *(const f16x8*)&Ax[(m0 + i * 16 + fr) * APAD + kb];
        #pragma unroll
        for (int j = 0; j < 3; j++) {
            int gb = (j * 16 + fr) * 128 + k0 + kb;
            bh[j] = *(const f16x8*)&Wt3h[gb];
            bl[j] = *(const f16x8*)&Wt3l[gb];
        }
        #pragma unroll
        for (int i = 0; i < 2; i++)
            #pragma unroll
            for (int j = 0; j < 3; j++) {
                acc[i][j] = __builtin_amdgcn_mfma_f32_16x16x32_f16(
                    a0[i], bh[j], acc[i][j], 0, 0, 0);
                acc[i][j] = __builtin_amdgcn_mfma_f32_16x16x32_f16(
                    a0[i], bl[j], acc[i][j], 0, 0, 0);
            }
        __syncthreads();
    }

    // epilogue: each output row lives in 16 consecutive lanes (3 cols/lane).
    // col = j*16 + fr (valid if <40); row = m0 + i*16 + (lane>>4)*4 + r.
    float bb[3];
    int cg[3];
    #pragma unroll
    for (int j = 0; j < 3; j++) {
        cg[j] = j * 16 + fr;
        bb[j] = (cg[j] < 40) ? b3[cg[j]] : 0.f;
    }
    float s1 = 0.f, s2 = 0.f;
    #pragma unroll
    for (int i = 0; i < 2; i++) {
        #pragma unroll
        for (int r = 0; r < 4; r++) {
            int row = r0 + m0 + i * 16 + (lane >> 4) * 4 + r;
            float vv[3];
            float mx = -INFINITY;
            #pragma unroll
            for (int j = 0; j < 3; j++) {
                vv[j] = acc[i][j][r] + bb[j];
                if (cg[j] < 40) mx = fmaxf(mx, vv[j]);
            }
            mx = fmaxf(mx, __shfl_xor(mx, 1));
            mx = fmaxf(mx, __shfl_xor(mx, 2));
            mx = fmaxf(mx, __shfl_xor(mx, 4));
            mx = fmaxf(mx, __shfl_xor(mx, 8));
            float se = 0.f;
            #pragma unroll
            for (int j = 0; j < 3; j++)
                if (cg[j] < 40) se += expf(vv[j] - mx);
            se += __shfl_xor(se, 1);
            se += __shfl_xor(se, 2);
            se += __shfl_xor(se, 4);
            se += __shfl_xor(se, 8);
            float ls = mx + logf(se);
            if (row < M) {
                #pragma unroll
                for (int j = 0; j < 3; j++) {
                    if (cg[j] < 40) {
                        out[(size_t)row * 40 + cg[j]] = vv[j] - ls;
                        s1 += vv[j];
                        s2 += vv[j] * vv[j];
                    }
                }
            }
        }
    }
    #pragma unroll
    for (int o = 32; o; o >>= 1) { s1 += __shfl_xor(s1, o); s2 += __shfl_xor(s2, o); }
    __shared__ double sh1[4], sh2[4];
    if (lane == 0) { sh1[w] = (double)s1; sh2[w] = (double)s2; }
    __syncthreads();
    if (t == 0) {
        atomicAdd(&scal[0], sh1[0] + sh1[1] + sh1[2] + sh1[3]);
        atomicAdd(&scal[1], sh2[0] + sh2[1] + sh2[2] + sh2[3]);
        __threadfence();
        int prev = atomicAdd(done, 1);
        if (prev == (int)gridDim.x - 1) {          // last block finalizes var
            __threadfence();
            double t1 = atomicAdd(&scal[0], 0.0);  // coherent read
            double t2 = atomicAdd(&scal[1], 0.0);
            long long nn = (long long)M * 40;
            out[nn] = (float)((t2 - t1 * t1 / (double)nn) / (double)(nn - 1));
        }
    }
}

// ---------------- launch ----------------
extern "C" void kernel_launch(void* const* d_in, const int* in_sizes, int n_in,
                              void* d_out, int out_size, void* d_ws, size_t ws_size,
                              hipStream_t stream) {
    const float* x   = (const float*)d_in[0];
    const void*  ei  = d_in[1];
    const float* W1  = (const float*)d_in[2];
    const float* b1  = (const float*)d_in[3];
    const float* g1  = (const float*)d_in[4];
    const float* be1 = (const float*)d_in[5];
    const float* m1  = (const float*)d_in[6];
    const float* v1  = (const float*)d_in[7];
    const float* W2  = (const float*)d_in[8];
    const float* b2  = (const float*)d_in[9];
    const float* g2  = (const float*)d_in[10];
    const float* be2 = (const float*)d_in[11];
    const float* m2  = (const float*)d_in[12];
    const float* v2  = (const float*)d_in[13];
    const float* W3  = (const float*)d_in[14];
    const float* b3  = (const float*)d_in[15];

    const int n = in_sizes[0] / 128;   // 169343 nodes
    const int E = in_sizes[1] / 2;     // 1166243 edges
    float* out = (float*)d_out;

    // workspace layout (all 16B-aligned):
    // scal[2] dbl | A[nh f16] | B[nh f16] | dinv[npad f32] | deg_i[npad]
    // | rowptr[npad+4] | rank[Epad] | bsum[128] | boff[128] | flag[4]
    // | done[4] | col[Epad] | Wt1h/l | Wt2h/l (128*128 f16) | Wt3h/l (48*128)
    size_t nh   = (size_t)n * 128;
    size_t npad = ((size_t)n + 3) & ~(size_t)3;
    size_t Epad = ((size_t)E + 3) & ~(size_t)3;
    double* scal   = (double*)d_ws;
    f16*    A      = (f16*)(scal + 2);
    f16*    B      = A + nh;
    float*  dinv   = (float*)(B + nh);
    int*    deg_i  = (int*)(dinv + npad);
    int*    rowptr = deg_i + npad;
    int*    rank   = rowptr + npad + 4;
    int*    bsum   = rank + Epad;
    int*    boff   = bsum + 128;
    int*    flag   = boff + 128;
    int*    done   = flag + 4;
    int*    col    = done + 4;
    f16*    Wt1h   = (f16*)(col + Epad);
    f16*    Wt1l   = Wt1h + 128 * 128;
    f16*    Wt2h   = Wt1l + 128 * 128;
    f16*    Wt2l   = Wt2h + 128 * 128;
    f16*    Wt3h   = Wt2l + 128 * 128;
    f16*    Wt3l   = Wt3h + 48 * 128;

    const int nb_n   = (n + 255) / 256;
    const int nb_e4  = (E + 1023) / 1024;
    const int nb_gm  = (n + 127) / 128;
    const int nb_agg = (n + 7) / 8;
    const int nb_sc  = (n + 2047) / 2048;

    init_kernel<<<nb_n, 256, 0, stream>>>(ei, flag, deg_i, scal, done, n);
    degi_kernel<<<nb_e4, 256, 0, stream>>>(ei, flag, deg_i, rank, E);
    prep_w_kernel<<<160, 256, 0, stream>>>(W1, Wt1h, Wt1l, W2, Wt2h, Wt2l,
                                           W3, Wt3h, Wt3l);

    // CSR build (atomic-free fill via rank)
    scan1_kernel<<<nb_sc, 256, 0, stream>>>(deg_i, rowptr, bsum, n);
    scan1_kernel<<<1, 256, 0, stream>>>(bsum, boff, nullptr, nb_sc);
    scan3_kernel<<<nb_n, 256, 0, stream>>>(rowptr, boff, deg_i, dinv, n, E);
    fill_kernel<<<nb_e4, 256, 0, stream>>>(ei, flag, rowptr, rank, col, E);

    // layer 1
    gemm_l1_kernel<<<nb_gm, 256, 0, stream>>>(x, Wt1h, Wt1l, dinv, A, n);
    agg_kernel<<<nb_agg, 256, 0, stream>>>(A, rowptr, col, dinv,
                                           b1, g1, be1, m1, v1, B, n);
    // layer 2
    gemm_l2_kernel<<<nb_gm, 256, 0, stream>>>(B, Wt2h, Wt2l, dinv, A, n);
    agg_kernel<<<nb_agg, 256, 0, stream>>>(A, rowptr, col, dinv,
                                           b2, g2, be2, m2, v2, B, n);
    // output layer: MFMA GEMM + fused log_softmax + var finalize
    gemm_out_kernel<<<nb_gm, 256, 0, stream>>>(B, Wt3h, Wt3l, b3, out,
                                               scal, done, n);
}

// Round 13
// 516.887 us; speedup vs baseline: 1.0960x; 1.0960x over previous
//
#include <hip/hip_runtime.h>
#include <math.h>

#define BN_EPS 1e-5f

typedef _Float16 f16;
typedef __attribute__((ext_vector_type(4))) _Float16 f16x4;
typedef __attribute__((ext_vector_type(8))) _Float16 f16x8;
typedef __attribute__((ext_vector_type(4))) float f32x4;

// ---------------- edge dtype handling (int32 vs int64) ----------------
__device__ __forceinline__ int edge_at(const void* ei, long long idx, int is64) {
    if (is64) return (int)((const long long*)ei)[idx];
    return ((const int*)ei)[idx];
}

// ------- init: zero degrees + int64-detect --------
__global__ void init_kernel(const void* ei, int* flag, int* deg_i, int n) {
    int i = blockIdx.x * 256 + threadIdx.x;
    if (i < n) deg_i[i] = 0;
    if (blockIdx.x == 0 && threadIdx.x == 0) {
        const int* p = (const int*)ei;
        int f = 1;
        for (int k = 0; k < 64; k++)
            if (p[2 * k + 1] != 0) { f = 0; break; }
        *flag = f;          // int64 iff every high word of 64 entries is 0
    }
}

// ---- degree count; atomic's old value IS this edge's rank within dst ------
__global__ void degi_kernel(const void* ei, const int* flag, int* deg_i,
                            int* __restrict__ rank, int E) {
    const int base = blockIdx.x * 1024 + threadIdx.x;
    const int is64 = *flag;
    #pragma unroll
    for (int k = 0; k < 4; k++) {
        int e = base + k * 256;
        if (e < E) {
            int d = edge_at(ei, (long long)E + e, is64);
            rank[e] = atomicAdd(&deg_i[d], 1);   // coalesced rank write
        }
    }
}

// ---------------- exclusive scan (2048 elems/block) ------------------------
__global__ __launch_bounds__(256) void scan1_kernel(
    const int* __restrict__ in, int* __restrict__ excl, int* bsum, int n) {
    __shared__ int sh[256];
    const int tid = threadIdx.x;
    const int base = blockIdx.x * 2048 + tid * 8;
    int v[8];
    #pragma unroll
    for (int i = 0; i < 8; i++) v[i] = (base + i < n) ? in[base + i] : 0;
    int tsum = 0;
    #pragma unroll
    for (int i = 0; i < 8; i++) { int t = v[i]; v[i] = tsum; tsum += t; }
    sh[tid] = tsum;
    __syncthreads();
    for (int off = 1; off < 256; off <<= 1) {
        int t = 0;
        if (tid >= off) t = sh[tid - off];
        __syncthreads();
        if (tid >= off) sh[tid] += t;
        __syncthreads();
    }
    int texcl = sh[tid] - tsum;
    #pragma unroll
    for (int i = 0; i < 8; i++)
        if (base + i < n) excl[base + i] = texcl + v[i];
    if (tid == 255 && bsum) bsum[blockIdx.x] = sh[255];
}

// scan3 + dinv fused
__global__ void scan3_kernel(int* rowptr, const int* __restrict__ boff,
                             const int* __restrict__ deg_i,
                             float* __restrict__ dinv, int n, int E) {
    int i = blockIdx.x * 256 + threadIdx.x;
    if (i < n) {
        rowptr[i] = rowptr[i] + boff[i >> 11];
        dinv[i] = rsqrtf((float)(deg_i[i] + 1));   // +1 self-loop
    }
    if (i == 0) rowptr[n] = E;
}

// ---- atomic-free fill: pos = rowptr[dst] + rank; nt store ------------------
__global__ void fill_kernel(const void* ei, const int* flag,
                            const int* __restrict__ rowptr,
                            const int* __restrict__ rank,
                            int* __restrict__ col, int E) {
    const int base = blockIdx.x * 1024 + threadIdx.x;
    const int is64 = *flag;
    #pragma unroll
    for (int k = 0; k < 4; k++) {
        int e = base + k * 256;
        if (e < E) {
            int s = edge_at(ei, e, is64);
            int d = edge_at(ei, (long long)E + e, is64);
            __builtin_nontemporal_store(s, &col[rowptr[d] + rank[e]]);
        }
    }
}

// ---- W prep: W1,W2 transpose + f16 hi/lo split; W3 [128][40]->[48][128] ----
__global__ __launch_bounds__(256) void prep_w_kernel(
    const float* __restrict__ W1, f16* __restrict__ Wt1h, f16* __restrict__ Wt1l,
    const float* __restrict__ W2, f16* __restrict__ Wt2h, f16* __restrict__ Wt2l,
    const float* __restrict__ W3, f16* __restrict__ Wt3h, f16* __restrict__ Wt3l) {
    const int total = 2 * 16384 + 48 * 128;
    for (int f = blockIdx.x * 256 + threadIdx.x; f < total;
         f += gridDim.x * 256) {
        if (f < 2 * 16384) {
            int which = f >> 14, g = f & 16383;
            int k = g >> 7, nn = g & 127;
            const float* W = which ? W2 : W1;
            f16* Wh = which ? Wt2h : Wt1h;
            f16* Wl = which ? Wt2l : Wt1l;
            float wv = W[g];
            f16 h = (f16)wv;
            Wh[nn * 128 + k] = h;
            Wl[nn * 128 + k] = (f16)(wv - (float)h);
        } else {
            int g = f - 2 * 16384;        // 0..6143
            int nn = g >> 7, k = g & 127; // col nn (0..47), row k
            float wv = (nn < 40) ? W3[k * 40 + nn] : 0.f;
            f16 h = (f16)wv;
            Wt3h[g] = h;
            Wt3l[g] = (f16)(wv - (float)h);
        }
    }
}

// ---------------- layer-1 MFMA GEMM: fp32 in, fp16 out, 2-pass ------------
#define APAD 40   // padded k-stride (halves): 80B rows
__global__ __launch_bounds__(256) void gemm_l1_kernel(
    const float* __restrict__ X, const f16* __restrict__ Wth,
    const f16* __restrict__ Wtl, const float* __restrict__ dinv,
    f16* __restrict__ out, int M) {
    __shared__ f16 Ah[128 * APAD];
    __shared__ f16 Bh[128 * APAD];
    __shared__ f16 Bl[128 * APAD];
    const int t = threadIdx.x;
    const int r0 = blockIdx.x * 128;
    const int w = t >> 6, lane = t & 63;
    const int m0 = (w >> 1) * 64, n0 = (w & 1) * 64;
    const int fr = lane & 15;
    const int kb = (lane >> 4) * 8;

    f32x4 acc[4][4];
    #pragma unroll
    for (int i = 0; i < 4; i++)
        #pragma unroll
        for (int j = 0; j < 4; j++) acc[i][j] = (f32x4)0.f;

    for (int k0 = 0; k0 < 128; k0 += 32) {
        #pragma unroll
        for (int i = 0; i < 4; i++) {
            int f = t + i * 256;               // 0..1023
            int row = f >> 3, kq = (f & 7) * 4;
            float4 v = make_float4(0.f, 0.f, 0.f, 0.f);
            if (r0 + row < M)
                v = *(const float4*)&X[(size_t)(r0 + row) * 128 + k0 + kq];
            *(f16x4*)&Ah[row * APAD + kq] =
                (f16x4){(f16)v.x, (f16)v.y, (f16)v.z, (f16)v.w};
        }
        #pragma unroll
        for (int i = 0; i < 2; i++) {
            int f = t + i * 256;               // 0..511
            int nrow = f >> 2, kq = (f & 3) * 8;
            int gb = nrow * 128 + k0 + kq;
            int lb = nrow * APAD + kq;
            *(uint4*)&Bh[lb] = *(const uint4*)&Wth[gb];
            *(uint4*)&Bl[lb] = *(const uint4*)&Wtl[gb];
        }
        __syncthreads();

        f16x8 a0[4], b0[4], xx[4];
        #pragma unroll
        for (int i = 0; i < 4; i++) {
            a0[i] = *(const f16x8*)&Ah[(m0 + i * 16 + fr) * APAD + kb];
            b0[i] = *(const f16x8*)&Bh[(n0 + i * 16 + fr) * APAD + kb];
        }
        #pragma unroll
        for (int i = 0; i < 4; i++)
            #pragma unroll
            for (int j = 0; j < 4; j++)
                acc[i][j] = __builtin_amdgcn_mfma_f32_16x16x32_f16(
                    a0[i], b0[j], acc[i][j], 0, 0, 0);
        #pragma unroll
        for (int i = 0; i < 4; i++)
            xx[i] = *(const f16x8*)&Bl[(n0 + i * 16 + fr) * APAD + kb];
        #pragma unroll
        for (int i = 0; i < 4; i++)
            #pragma unroll
            for (int j = 0; j < 4; j++)
                acc[i][j] = __builtin_amdgcn_mfma_f32_16x16x32_f16(
                    a0[i], xx[j], acc[i][j], 0, 0, 0);
        __syncthreads();
    }

    // C/D layout: col=lane&15, row=(lane>>4)*4+reg (m89-verified)
    #pragma unroll
    for (int i = 0; i < 4; i++) {
        #pragma unroll
        for (int r = 0; r < 4; r++) {
            int row = r0 + m0 + i * 16 + (lane >> 4) * 4 + r;
            if (row < M) {
                float di = dinv[row];
                #pragma unroll
                for (int j = 0; j < 4; j++)
                    out[(size_t)row * 128 + n0 + j * 16 + fr] =
                        (f16)(acc[i][j][r] * di);
            }
        }
    }
}

// ---------------- layer-2 MFMA GEMM: fp16 in, fp16 out, 2-pass ------------
__global__ __launch_bounds__(256) void gemm_l2_kernel(
    const f16* __restrict__ X, const f16* __restrict__ Wth,
    const f16* __restrict__ Wtl, const float* __restrict__ dinv,
    f16* __restrict__ out, int M) {
    __shared__ f16 Ax[128 * APAD];
    __shared__ f16 Bh[128 * APAD];
    __shared__ f16 Bl[128 * APAD];
    const int t = threadIdx.x;
    const int r0 = blockIdx.x * 128;
    const int w = t >> 6, lane = t & 63;
    const int m0 = (w >> 1) * 64, n0 = (w & 1) * 64;
    const int fr = lane & 15;
    const int kb = (lane >> 4) * 8;

    f32x4 acc[4][4];
    #pragma unroll
    for (int i = 0; i < 4; i++)
        #pragma unroll
        for (int j = 0; j < 4; j++) acc[i][j] = (f32x4)0.f;

    for (int k0 = 0; k0 < 128; k0 += 32) {
        #pragma unroll
        for (int i = 0; i < 2; i++) {
            int f = t + i * 256;               // 0..511
            int row = f >> 2, kq = (f & 3) * 8;
            uint4 v = make_uint4(0u, 0u, 0u, 0u);
            if (r0 + row < M)
                v = *(const uint4*)&X[(size_t)(r0 + row) * 128 + k0 + kq];
            *(uint4*)&Ax[row * APAD + kq] = v;
        }
        #pragma unroll
        for (int i = 0; i < 2; i++) {
            int f = t + i * 256;
            int nrow = f >> 2, kq = (f & 3) * 8;
            int gb = nrow * 128 + k0 + kq;
            int lb = nrow * APAD + kq;
            *(uint4*)&Bh[lb] = *(const uint4*)&Wth[gb];
            *(uint4*)&Bl[lb] = *(const uint4*)&Wtl[gb];
        }
        __syncthreads();

        f16x8 a0[4], b0[4], xx[4];
        #pragma unroll
        for (int i = 0; i < 4; i++) {
            a0[i] = *(const f16x8*)&Ax[(m0 + i * 16 + fr) * APAD + kb];
            b0[i] = *(const f16x8*)&Bh[(n0 + i * 16 + fr) * APAD + kb];
        }
        #pragma unroll
        for (int i = 0; i < 4; i++)
            #pragma unroll
            for (int j = 0; j < 4; j++)
                acc[i][j] = __builtin_amdgcn_mfma_f32_16x16x32_f16(
                    a0[i], b0[j], acc[i][j], 0, 0, 0);
        #pragma unroll
        for (int i = 0; i < 4; i++)
            xx[i] = *(const f16x8*)&Bl[(n0 + i * 16 + fr) * APAD + kb];
        #pragma unroll
        for (int i = 0; i < 4; i++)
            #pragma unroll
            for (int j = 0; j < 4; j++)
                acc[i][j] = __builtin_amdgcn_mfma_f32_16x16x32_f16(
                    a0[i], xx[j], acc[i][j], 0, 0, 0);
        __syncthreads();
    }

    #pragma unroll
    for (int i = 0; i < 4; i++) {
        #pragma unroll
        for (int r = 0; r < 4; r++) {
            int row = r0 + m0 + i * 16 + (lane >> 4) * 4 + r;
            if (row < M) {
                float di = dinv[row];
                #pragma unroll
                for (int j = 0; j < 4; j++)
                    out[(size_t)row * 128 + n0 + j * 16 + fr] =
                        (f16)(acc[i][j][r] * di);
            }
        }
    }
}

// ---------------- fused pull-aggregate + bias + relu + BN + relu ----------
// Half-wave (32 lanes) per node; 4-deep ILP (round-8 proven form).
__global__ __launch_bounds__(256) void agg_kernel(
    const f16* __restrict__ hs, const int* __restrict__ rowptr,
    const int* __restrict__ col, const float* __restrict__ dinv,
    const float* __restrict__ b, const float* __restrict__ g,
    const float* __restrict__ be, const float* __restrict__ m,
    const float* __restrict__ v, f16* __restrict__ h, int M) {
    const int node = blockIdx.x * 8 + (threadIdx.x >> 5);
    if (node >= M) return;
    const int lane = threadIdx.x & 31;
    const int c = lane * 4;
    const f16* __restrict__ base = hs + c;

    f16x4 sv = *(const f16x4*)&base[(size_t)node * 128];   // self-loop term
    float a0[4] = {(float)sv[0], (float)sv[1], (float)sv[2], (float)sv[3]};
    float a1[4] = {0.f, 0.f, 0.f, 0.f};
    float a2[4] = {0.f, 0.f, 0.f, 0.f};
    float a3[4] = {0.f, 0.f, 0.f, 0.f};
    const int beg = rowptr[node], end = rowptr[node + 1];
    int j = beg;
    for (; j + 3 < end; j += 4) {       // 4 independent loads in flight
        int s0 = col[j], s1 = col[j + 1], s2 = col[j + 2], s3 = col[j + 3];
        f16x4 v0 = *(const f16x4*)&base[(size_t)s0 * 128];
        f16x4 v1 = *(const f16x4*)&base[(size_t)s1 * 128];
        f16x4 v2 = *(const f16x4*)&base[(size_t)s2 * 128];
        f16x4 v3 = *(const f16x4*)&base[(size_t)s3 * 128];
        #pragma unroll
        for (int q = 0; q < 4; q++) {
            a0[q] += (float)v0[q]; a1[q] += (float)v1[q];
            a2[q] += (float)v2[q]; a3[q] += (float)v3[q];
        }
    }
    if (j + 1 < end) {                  // 2-tail
        int s0 = col[j], s1 = col[j + 1];
        f16x4 v0 = *(const f16x4*)&base[(size_t)s0 * 128];
        f16x4 v1 = *(const f16x4*)&base[(size_t)s1 * 128];
        #pragma unroll
        for (int q = 0; q < 4; q++) { a0[q] += (float)v0[q]; a1[q] += (float)v1[q]; }
        j += 2;
    }
    if (j < end) {                      // 1-tail
        int s0 = col[j];
        f16x4 v0 = *(const f16x4*)&base[(size_t)s0 * 128];
        #pragma unroll
        for (int q = 0; q < 4; q++) a0[q] += (float)v0[q];
    }
    const float di = dinv[node];
    f16x4 r;
    #pragma unroll
    for (int q = 0; q < 4; q++) {
        int cc = c + q;
        float s = (a0[q] + a1[q]) + (a2[q] + a3[q]);
        float tt = fmaxf(di * s + b[cc], 0.f);
        tt = (tt - m[cc]) * (g[cc] * rsqrtf(v[cc] + BN_EPS)) + be[cc];
        r[q] = (f16)fmaxf(tt, 0.f);
    }
    *(f16x4*)&h[(size_t)node * 128 + c] = r;
}

// ------- output GEMM (MFMA) + fused log_softmax; per-block var partials ----
// Tile: 128 rows x 48 cols (40 valid). 4 waves x 32 rows. W3t read from
// global (24KB, L1/L2 resident). NO cross-block atomics: partials to part[].
__global__ __launch_bounds__(256) void gemm_out_kernel(
    const f16* __restrict__ H, const f16* __restrict__ Wt3h,
    const f16* __restrict__ Wt3l, const float* __restrict__ b3,
    float* __restrict__ out, double* __restrict__ part, int M) {
    __shared__ f16 Ax[128 * APAD];
    const int t = threadIdx.x;
    const int r0 = blockIdx.x * 128;
    const int w = t >> 6, lane = t & 63;
    const int m0 = w * 32;
    const int fr = lane & 15;
    const int kb = (lane >> 4) * 8;

    f32x4 acc[2][3];
    #pragma unroll
    for (int i = 0; i < 2; i++)
        #pragma unroll
        for (int j = 0; j < 3; j++) acc[i][j] = (f32x4)0.f;

    for (int k0 = 0; k0 < 128; k0 += 32) {
        #pragma unroll
        for (int i = 0; i < 2; i++) {
            int f = t + i * 256;               // 0..511
            int row = f >> 2, kq = (f & 3) * 8;
            uint4 v = make_uint4(0u, 0u, 0u, 0u);
            if (r0 + row < M)
                v = *(const uint4*)&H[(size_t)(r0 + row) * 128 + k0 + kq];
            *(uint4*)&Ax[row * APAD + kq] = v;
        }
        __syncthreads();

        f16x8 a0[2], bh[3], bl[3];
        #pragma unroll
        for (int i = 0; i < 2; i++)
            a0[i] = *(const f16x8*)&Ax[(m0 + i * 16 + fr) * APAD + kb];
        #pragma unroll
        for (int j = 0; j < 3; j++) {
            int gb = (j * 16 + fr) * 128 + k0 + kb;
            bh[j] = *(const f16x8*)&Wt3h[gb];
            bl[j] = *(const f16x8*)&Wt3l[gb];
        }
        #pragma unroll
        for (int i = 0; i < 2; i++)
            #pragma unroll
            for (int j = 0; j < 3; j++) {
                acc[i][j] = __builtin_amdgcn_mfma_f32_16x16x32_f16(
                    a0[i], bh[j], acc[i][j], 0, 0, 0);
                acc[i][j] = __builtin_amdgcn_mfma_f32_16x16x32_f16(
                    a0[i], bl[j], acc[i][j], 0, 0, 0);
            }
        __syncthreads();
    }

    // epilogue: each output row lives in 16 consecutive lanes (3 cols/lane).
    float bb[3];
    int cg[3];
    #pragma unroll
    for (int j = 0; j < 3; j++) {
        cg[j] = j * 16 + fr;
        bb[j] = (cg[j] < 40) ? b3[cg[j]] : 0.f;
    }
    float s1 = 0.f, s2 = 0.f;
    #pragma unroll
    for (int i = 0; i < 2; i++) {
        #pragma unroll
        for (int r = 0; r < 4; r++) {
            int row = r0 + m0 + i * 16 + (lane >> 4) * 4 + r;
            float vv[3];
            float mx = -INFINITY;
            #pragma unroll
            for (int j = 0; j < 3; j++) {
                vv[j] = acc[i][j][r] + bb[j];
                if (cg[j] < 40) mx = fmaxf(mx, vv[j]);
            }
            mx = fmaxf(mx, __shfl_xor(mx, 1));
            mx = fmaxf(mx, __shfl_xor(mx, 2));
            mx = fmaxf(mx, __shfl_xor(mx, 4));
            mx = fmaxf(mx, __shfl_xor(mx, 8));
            float se = 0.f;
            #pragma unroll
            for (int j = 0; j < 3; j++)
                if (cg[j] < 40) se += expf(vv[j] - mx);
            se += __shfl_xor(se, 1);
            se += __shfl_xor(se, 2);
            se += __shfl_xor(se, 4);
            se += __shfl_xor(se, 8);
            float ls = mx + logf(se);
            if (row < M) {
                #pragma unroll
                for (int j = 0; j < 3; j++) {
                    if (cg[j] < 40) {
                        out[(size_t)row * 40 + cg[j]] = vv[j] - ls;
                        s1 += vv[j];
                        s2 += vv[j] * vv[j];
                    }
                }
            }
        }
    }
    #pragma unroll
    for (int o = 32; o; o >>= 1) { s1 += __shfl_xor(s1, o); s2 += __shfl_xor(s2, o); }
    __shared__ double sh1[4], sh2[4];
    if (lane == 0) { sh1[w] = (double)s1; sh2[w] = (double)s2; }
    __syncthreads();
    if (t == 0) {                               // contention-free partials
        part[2 * blockIdx.x]     = sh1[0] + sh1[1] + sh1[2] + sh1[3];
        part[2 * blockIdx.x + 1] = sh2[0] + sh2[1] + sh2[2] + sh2[3];
    }
}

// ---- var finalize: reduce per-block partials (1 block, 21KB read) ---------
__global__ __launch_bounds__(256) void var_kernel(
    const double* __restrict__ part, int nb, float* out, long long nn) {
    double s1 = 0.0, s2 = 0.0;
    for (int i = threadIdx.x; i < nb; i += 256) {
        s1 += part[2 * i];
        s2 += part[2 * i + 1];
    }
    #pragma unroll
    for (int o = 32; o; o >>= 1) {
        s1 += __shfl_xor(s1, o);
        s2 += __shfl_xor(s2, o);
    }
    __shared__ double a1[4], a2[4];
    int wv = threadIdx.x >> 6;
    if ((threadIdx.x & 63) == 0) { a1[wv] = s1; a2[wv] = s2; }
    __syncthreads();
    if (threadIdx.x == 0) {
        double t1 = a1[0] + a1[1] + a1[2] + a1[3];
        double t2 = a2[0] + a2[1] + a2[2] + a2[3];
        out[nn] = (float)((t2 - t1 * t1 / (double)nn) / (double)(nn - 1));
    }
}

// ---------------- launch ----------------
extern "C" void kernel_launch(void* const* d_in, const int* in_sizes, int n_in,
                              void* d_out, int out_size, void* d_ws, size_t ws_size,
                              hipStream_t stream) {
    const float* x   = (const float*)d_in[0];
    const void*  ei  = d_in[1];
    const float* W1  = (const float*)d_in[2];
    const float* b1  = (const float*)d_in[3];
    const float* g1  = (const float*)d_in[4];
    const float* be1 = (const float*)d_in[5];
    const float* m1  = (const float*)d_in[6];
    const float* v1  = (const float*)d_in[7];
    const float* W2  = (const float*)d_in[8];
    const float* b2  = (const float*)d_in[9];
    const float* g2  = (const float*)d_in[10];
    const float* be2 = (const float*)d_in[11];
    const float* m2  = (const float*)d_in[12];
    const float* v2  = (const float*)d_in[13];
    const float* W3  = (const float*)d_in[14];
    const float* b3  = (const float*)d_in[15];

    const int n = in_sizes[0] / 128;   // 169343 nodes
    const int E = in_sizes[1] / 2;     // 1166243 edges
    float* out = (float*)d_out;

    const int nb_n   = (n + 255) / 256;
    const int nb_e4  = (E + 1023) / 1024;
    const int nb_gm  = (n + 127) / 128;
    const int nb_agg = (n + 7) / 8;
    const int nb_sc  = (n + 2047) / 2048;

    // workspace layout (all 16B-aligned):
    // part[2*nb_gm dbl] | A[nh f16] | B[nh f16] | dinv[npad f32] | deg_i[npad]
    // | rowptr[npad+4] | rank[Epad] | bsum[128] | boff[128] | flag[4]
    // | col[Epad] | Wt1h/l | Wt2h/l (128*128 f16) | Wt3h/l (48*128 f16)
    size_t nh   = (size_t)n * 128;
    size_t npad = ((size_t)n + 3) & ~(size_t)3;
    size_t Epad = ((size_t)E + 3) & ~(size_t)3;
    size_t ppad = ((size_t)(2 * nb_gm) + 1) & ~(size_t)1;
    double* part   = (double*)d_ws;
    f16*    A      = (f16*)(part + ppad);
    f16*    B      = A + nh;
    float*  dinv   = (float*)(B + nh);
    int*    deg_i  = (int*)(dinv + npad);
    int*    rowptr = deg_i + npad;
    int*    rank   = rowptr + npad + 4;
    int*    bsum   = rank + Epad;
    int*    boff   = bsum + 128;
    int*    flag   = boff + 128;
    int*    col    = flag + 4;
    f16*    Wt1h   = (f16*)(col + Epad);
    f16*    Wt1l   = Wt1h + 128 * 128;
    f16*    Wt2h   = Wt1l + 128 * 128;
    f16*    Wt2l   = Wt2h + 128 * 128;
    f16*    Wt3h   = Wt2l + 128 * 128;
    f16*    Wt3l   = Wt3h + 48 * 128;

    init_kernel<<<nb_n, 256, 0, stream>>>(ei, flag, deg_i, n);
    degi_kernel<<<nb_e4, 256, 0, stream>>>(ei, flag, deg_i, rank, E);
    prep_w_kernel<<<160, 256, 0, stream>>>(W1, Wt1h, Wt1l, W2, Wt2h, Wt2l,
                                           W3, Wt3h, Wt3l);

    // CSR build (atomic-free fill via rank)
    scan1_kernel<<<nb_sc, 256, 0, stream>>>(deg_i, rowptr, bsum, n);
    scan1_kernel<<<1, 256, 0, stream>>>(bsum, boff, nullptr, nb_sc);
    scan3_kernel<<<nb_n, 256, 0, stream>>>(rowptr, boff, deg_i, dinv, n, E);
    fill_kernel<<<nb_e4, 256, 0, stream>>>(ei, flag, rowptr, rank, col, E);

    // layer 1
    gemm_l1_kernel<<<nb_gm, 256, 0, stream>>>(x, Wt1h, Wt1l, dinv, A, n);
    agg_kernel<<<nb_agg, 256, 0, stream>>>(A, rowptr, col, dinv,
                                           b1, g1, be1, m1, v1, B, n);
    // layer 2
    gemm_l2_kernel<<<nb_gm, 256, 0, stream>>>(B, Wt2h, Wt2l, dinv, A, n);
    agg_kernel<<<nb_agg, 256, 0, stream>>>(A, rowptr, col, dinv,
                                           b2, g2, be2, m2, v2, B, n);
    // output layer: MFMA GEMM + fused log_softmax (no cross-block atomics)
    gemm_out_kernel<<<nb_gm, 256, 0, stream>>>(B, Wt3h, Wt3l, b3, out, part, n);
    var_kernel<<<1, 256, 0, stream>>>(part, nb_gm, out, (long long)n * 40);
}